// Round 4
// baseline (456.548 us; speedup 1.0000x reference)
//
#include <hip/hip_runtime.h>
#include <math.h>

// ETM forward. B=1024 S=512 V=50000 E=300 H=800 T=50.
// k0: zero xbar/topicsum/loss + transpose alpha->aT
// k4: betaU=exp(rho@alphaT) (bf16 out, 128B rows) + topicsum; y=0 emits bf16 rho
// k1: token compaction (y=2 halves) + x partial sums from bf16 rho gather
// k2: h=relu(x/n @ W1 + b1)   k3: mu/lv/theta/kl   k6: recon + loss
// bows never materialized (sparse: <=512 tokens/row).

#define Bn 1024
#define Sn 512
#define Vn 50000
#define En 300
#define Hn 800
#define Tn 50
#define TSPLIT 2
#define Tc (Tn / TSPLIT)   // 25 topics per k4 y-slice
#define VT 512             // v-tile per block (2 per thread)
#define EC 12              // e-chunk (300 = 25 * 12)
#define BSTR 64            // betaU bf16 row stride (ushorts) = 128 B

__device__ __forceinline__ float waveReduceSum(float v) {
    #pragma unroll
    for (int off = 32; off > 0; off >>= 1) v += __shfl_xor(v, off, 64);
    return v;
}
__device__ __forceinline__ float waveReduceMax(float v) {
    #pragma unroll
    for (int off = 32; off > 0; off >>= 1) v = fmaxf(v, __shfl_xor(v, off, 64));
    return v;
}
__device__ __forceinline__ unsigned short f2bf(float x) {
    unsigned u = __float_as_uint(x);
    return (unsigned short)((u + 0x7FFFu + ((u >> 16) & 1u)) >> 16);
}
__device__ __forceinline__ float bf_lo(unsigned u) { return __uint_as_float(u << 16); }
__device__ __forceinline__ float bf_hi(unsigned u) { return __uint_as_float(u & 0xFFFF0000u); }

// Zero xbar/topicsum/loss; transpose alpha[t][e] -> aT[e*64 + t].
__global__ __launch_bounds__(256) void k0_init(
        const float* __restrict__ alpha, float* __restrict__ aT,
        float* __restrict__ topicsum, float* __restrict__ loss,
        float* __restrict__ xbar) {
    const int gid = blockIdx.x * 256 + threadIdx.x;
    if (blockIdx.x == 0) {
        if (threadIdx.x < Tn) topicsum[threadIdx.x] = 0.f;
        if (threadIdx.x == 63) *loss = 0.f;
    }
    if (gid < Bn * En) xbar[gid] = 0.f;
    if (gid < Tn * En) {
        int t = gid / En, e = gid - t * En;
        aT[e * 64 + t] = alpha[t * En + e];
    }
}

// betaU[v,t] = exp(sum_e rho[v,e]*alpha[t,e]) stored bf16 at row stride 64;
// topicsum[t] += sum_v. Thread owns v0+tid, v0+256+tid x 25 topics.
// y==0 blocks also emit rhoh = bf16(rho) during staging.
__global__ __launch_bounds__(256) void k4_beta(
        const float* __restrict__ rho, const float* __restrict__ aT,
        unsigned short* __restrict__ betaUh, unsigned short* __restrict__ rhoh,
        float* __restrict__ topicsum) {
    __shared__ float tile[VT * (EC + 1)];    // 26.6 KB, stride 13 (odd)
    __shared__ float asl[En * 28];           // 33.6 KB, 16B-aligned rows
    __shared__ float wsum[4][Tc];
    const int v0 = blockIdx.x * VT, tid = threadIdx.x;
    const int t0 = blockIdx.y * Tc;
    const bool emit = (blockIdx.y == 0);

    for (int idx = tid; idx < En * Tc; idx += 256) {
        int e = idx / Tc, tt = idx - e * Tc;
        asl[e * 28 + tt] = aT[e * 64 + t0 + tt];
    }

    float acc0[Tc], acc1[Tc];
    #pragma unroll
    for (int t = 0; t < Tc; ++t) { acc0[t] = 0.f; acc1[t] = 0.f; }

    const int va = v0 + tid;            // < Vn always (last tile <= 49919)
    const int vb = v0 + 256 + tid;
    const bool valb = vb < Vn;

    for (int c = 0; c < En / EC; ++c) {
        const int e0 = c * EC;
        __syncthreads();
        for (int idx = tid; idx < VT * (EC / 4); idx += 256) {
            int vl = idx / (EC / 4), j = idx - vl * (EC / 4);
            int gv = v0 + vl;
            float4 r = make_float4(0.f, 0.f, 0.f, 0.f);
            if (gv < Vn) {
                r = *(const float4*)(rho + (size_t)gv * En + e0 + 4 * j);
                if (emit) {
                    ushort4 p; p.x = f2bf(r.x); p.y = f2bf(r.y);
                    p.z = f2bf(r.z); p.w = f2bf(r.w);
                    *(ushort4*)(rhoh + (size_t)gv * En + e0 + 4 * j) = p;  // 8B aligned
                }
            }
            float* dst = &tile[vl * (EC + 1) + 4 * j];
            dst[0] = r.x; dst[1] = r.y; dst[2] = r.z; dst[3] = r.w;
        }
        __syncthreads();
        #pragma unroll
        for (int e = 0; e < EC; ++e) {
            float r0 = tile[tid * (EC + 1) + e];
            float r1 = tile[(tid + 256) * (EC + 1) + e];
            const float* a = &asl[(e0 + e) * 28];
            float4 a0 = *(const float4*)(a);
            float4 a1 = *(const float4*)(a + 4);
            float4 a2 = *(const float4*)(a + 8);
            float4 a3 = *(const float4*)(a + 12);
            float4 a4 = *(const float4*)(a + 16);
            float4 a5 = *(const float4*)(a + 20);
            float  s24 = a[24];
            acc0[0] = fmaf(r0, a0.x, acc0[0]);   acc1[0] = fmaf(r1, a0.x, acc1[0]);
            acc0[1] = fmaf(r0, a0.y, acc0[1]);   acc1[1] = fmaf(r1, a0.y, acc1[1]);
            acc0[2] = fmaf(r0, a0.z, acc0[2]);   acc1[2] = fmaf(r1, a0.z, acc1[2]);
            acc0[3] = fmaf(r0, a0.w, acc0[3]);   acc1[3] = fmaf(r1, a0.w, acc1[3]);
            acc0[4] = fmaf(r0, a1.x, acc0[4]);   acc1[4] = fmaf(r1, a1.x, acc1[4]);
            acc0[5] = fmaf(r0, a1.y, acc0[5]);   acc1[5] = fmaf(r1, a1.y, acc1[5]);
            acc0[6] = fmaf(r0, a1.z, acc0[6]);   acc1[6] = fmaf(r1, a1.z, acc1[6]);
            acc0[7] = fmaf(r0, a1.w, acc0[7]);   acc1[7] = fmaf(r1, a1.w, acc1[7]);
            acc0[8] = fmaf(r0, a2.x, acc0[8]);   acc1[8] = fmaf(r1, a2.x, acc1[8]);
            acc0[9] = fmaf(r0, a2.y, acc0[9]);   acc1[9] = fmaf(r1, a2.y, acc1[9]);
            acc0[10] = fmaf(r0, a2.z, acc0[10]); acc1[10] = fmaf(r1, a2.z, acc1[10]);
            acc0[11] = fmaf(r0, a2.w, acc0[11]); acc1[11] = fmaf(r1, a2.w, acc1[11]);
            acc0[12] = fmaf(r0, a3.x, acc0[12]); acc1[12] = fmaf(r1, a3.x, acc1[12]);
            acc0[13] = fmaf(r0, a3.y, acc0[13]); acc1[13] = fmaf(r1, a3.y, acc1[13]);
            acc0[14] = fmaf(r0, a3.z, acc0[14]); acc1[14] = fmaf(r1, a3.z, acc1[14]);
            acc0[15] = fmaf(r0, a3.w, acc0[15]); acc1[15] = fmaf(r1, a3.w, acc1[15]);
            acc0[16] = fmaf(r0, a4.x, acc0[16]); acc1[16] = fmaf(r1, a4.x, acc1[16]);
            acc0[17] = fmaf(r0, a4.y, acc0[17]); acc1[17] = fmaf(r1, a4.y, acc1[17]);
            acc0[18] = fmaf(r0, a4.z, acc0[18]); acc1[18] = fmaf(r1, a4.z, acc1[18]);
            acc0[19] = fmaf(r0, a4.w, acc0[19]); acc1[19] = fmaf(r1, a4.w, acc1[19]);
            acc0[20] = fmaf(r0, a5.x, acc0[20]); acc1[20] = fmaf(r1, a5.x, acc1[20]);
            acc0[21] = fmaf(r0, a5.y, acc0[21]); acc1[21] = fmaf(r1, a5.y, acc1[21]);
            acc0[22] = fmaf(r0, a5.z, acc0[22]); acc1[22] = fmaf(r1, a5.z, acc1[22]);
            acc0[23] = fmaf(r0, a5.w, acc0[23]); acc1[23] = fmaf(r1, a5.w, acc1[23]);
            acc0[24] = fmaf(r0, s24, acc0[24]);  acc1[24] = fmaf(r1, s24, acc1[24]);
        }
    }

    #pragma unroll
    for (int t = 0; t < Tc; ++t) {
        acc0[t] = expf(acc0[t]);
        acc1[t] = valb ? expf(acc1[t]) : 0.f;
    }
    #pragma unroll
    for (int t = 0; t < Tc; ++t)
        betaUh[(size_t)va * BSTR + t0 + t] = f2bf(acc0[t]);
    if (valb) {
        #pragma unroll
        for (int t = 0; t < Tc; ++t)
            betaUh[(size_t)vb * BSTR + t0 + t] = f2bf(acc1[t]);
    }
    const int wave = tid >> 6, lane = tid & 63;
    #pragma unroll
    for (int t = 0; t < Tc; ++t) {
        float s = waveReduceSum(acc0[t] + acc1[t]);
        if (lane == 0) wsum[wave][t] = s;
    }
    __syncthreads();
    if (tid < Tc) {
        atomicAdd(&topicsum[t0 + tid],
                  wsum[0][tid] + wsum[1][tid] + wsum[2][tid] + wsum[3][tid]);
    }
}

// Half-doc token compaction + unscaled x partial sums from bf16 rho gather.
// grid (Bn, 2). Lane p<150 owns e-pair (2p, 2p+1): one dword per token.
__global__ __launch_bounds__(256) void k1_tokens_x(
        const int* __restrict__ ids, const unsigned int* __restrict__ rhoh32,
        int* __restrict__ toks, int* __restrict__ cnt2,
        float* __restrict__ xbar) {
    __shared__ int sid[256];
    __shared__ int scount;
    const int b = blockIdx.x, half = blockIdx.y, tid = threadIdx.x;
    if (tid == 0) scount = 0;
    __syncthreads();
    int id = ids[b * Sn + half * 256 + tid];
    if (id != 1 && id != 2) {
        int p = atomicAdd(&scount, 1);
        sid[p] = id;
    }
    __syncthreads();
    const int n = scount;
    if (tid < n) toks[b * Sn + half * 256 + tid] = sid[tid];
    if (tid == 0) cnt2[b * 2 + half] = n;
    if (tid < En / 2) {
        float ax = 0.f, ay = 0.f;
        for (int s = 0; s < n; ++s) {
            unsigned u = rhoh32[sid[s] * (En / 2) + tid];
            ax += bf_lo(u);
            ay += bf_hi(u);
        }
        atomicAdd(&xbar[b * En + 2 * tid], ax);
        atomicAdd(&xbar[b * En + 2 * tid + 1], ay);
    }
}

// h = relu((xsum/n) @ W1 + b1): 8 rows/block; scale folded into staging.
__global__ __launch_bounds__(256) void k2_h(
        const float* __restrict__ xbar, const int* __restrict__ cnt2,
        const float* __restrict__ W1, const float* __restrict__ b1,
        float* __restrict__ h) {
    const int BR = 8;
    __shared__ float xs[BR * En];
    __shared__ float invn[BR];
    const int b0 = blockIdx.x * BR, tid = threadIdx.x;
    if (tid < BR) {
        int bb = b0 + tid;
        invn[tid] = 1.0f / (float)(cnt2[2 * bb] + cnt2[2 * bb + 1]);
    }
    __syncthreads();
    for (int i = tid; i < BR * En; i += 256) xs[i] = xbar[b0 * En + i] * invn[i / En];
    __syncthreads();
    const int j0 = tid, j1 = tid + 256, j2 = tid + 512, j3 = tid + 768;
    const bool has3 = (j3 < Hn);
    float acc[BR][4];
    #pragma unroll
    for (int r = 0; r < BR; ++r) {
        acc[r][0] = b1[j0]; acc[r][1] = b1[j1]; acc[r][2] = b1[j2];
        acc[r][3] = has3 ? b1[j3] : 0.f;
    }
    for (int e = 0; e < En; ++e) {
        float w0 = W1[e * Hn + j0];
        float w1 = W1[e * Hn + j1];
        float w2 = W1[e * Hn + j2];
        float w3 = has3 ? W1[e * Hn + j3] : 0.f;
        #pragma unroll
        for (int r = 0; r < BR; ++r) {
            float xv = xs[r * En + e];
            acc[r][0] += xv * w0; acc[r][1] += xv * w1;
            acc[r][2] += xv * w2; acc[r][3] += xv * w3;
        }
    }
    #pragma unroll
    for (int r = 0; r < BR; ++r) {
        h[(b0 + r) * Hn + j0] = fmaxf(acc[r][0], 0.f);
        h[(b0 + r) * Hn + j1] = fmaxf(acc[r][1], 0.f);
        h[(b0 + r) * Hn + j2] = fmaxf(acc[r][2], 0.f);
        if (has3) h[(b0 + r) * Hn + j3] = fmaxf(acc[r][3], 0.f);
    }
}

// mu/lv = h@Wmu/Wlv + bias; theta = softmax(mu); kl accumulated into loss.
__global__ __launch_bounds__(256) void k3_theta(
        const float* __restrict__ h, const float* __restrict__ Wmu,
        const float* __restrict__ bmu, const float* __restrict__ Wlv,
        const float* __restrict__ blv, float* __restrict__ theta,
        float* __restrict__ loss) {
    const int BR = 16;
    __shared__ float hs[BR * Hn];    // 51.2 KB
    const int b0 = blockIdx.x * BR, tid = threadIdx.x;
    for (int i = tid; i < BR * Hn; i += 256) hs[i] = h[b0 * Hn + i];
    __syncthreads();
    const int wave = tid >> 6, lane = tid & 63;
    const int t = (lane < Tn) ? lane : (Tn - 1);
    const bool act = (lane < Tn);
    float amu[4], alv[4];
    #pragma unroll
    for (int k = 0; k < 4; ++k) { amu[k] = bmu[t]; alv[k] = blv[t]; }
    const int rbase = wave * 4;
    for (int j = 0; j < Hn; ++j) {
        float wm = Wmu[j * Tn + t];
        float wl = Wlv[j * Tn + t];
        #pragma unroll
        for (int k = 0; k < 4; ++k) {
            float hv = hs[(rbase + k) * Hn + j];
            amu[k] += hv * wm;
            alv[k] += hv * wl;
        }
    }
    float klacc = 0.f;
    #pragma unroll
    for (int k = 0; k < 4; ++k) {
        float mu = amu[k], lv = alv[k];
        float m = waveReduceMax(act ? mu : -1e30f);
        float ex = act ? expf(mu - m) : 0.f;
        float ssum = waveReduceSum(ex);
        if (act) theta[(b0 + rbase + k) * Tn + lane] = ex / ssum;
        klacc += waveReduceSum(act ? (1.f + lv - mu * mu - expf(lv)) : 0.f);
    }
    if (lane == 0) atomicAdd(loss, -0.5f * klacc * (1.0f / (float)Bn));
}

// recon[b] = -sum_tok log( sum_t (theta/Z)[t] * betaU[tok,t] + 1e-5 ).
// betaU bf16, 128B rows: one cache line per token; uint4 loads.
__global__ __launch_bounds__(256) void k6_recon(
        const int* __restrict__ toks, const int* __restrict__ cnt2,
        const float* __restrict__ theta, const float* __restrict__ topicsum,
        const unsigned short* __restrict__ betaUh, float* __restrict__ loss) {
    __shared__ float sw[Tn];
    __shared__ float swred[4];
    const int b = blockIdx.x, tid = threadIdx.x;
    if (tid < Tn) sw[tid] = theta[b * Tn + tid] / topicsum[tid];
    __syncthreads();
    float wr[Tn];
    #pragma unroll
    for (int t = 0; t < Tn; ++t) wr[t] = sw[t];
    float lsum = 0.f;
    for (int half = 0; half < 2; ++half) {
        const int n = cnt2[b * 2 + half];
        for (int i = tid; i < n; i += 256) {
            int v = toks[b * Sn + half * 256 + i];
            const uint4* q = (const uint4*)(betaUh + (size_t)v * BSTR);
            float dot = 0.f;
            #pragma unroll
            for (int k = 0; k < 6; ++k) {
                uint4 u = q[k];
                int t = 8 * k;
                dot += wr[t]     * bf_lo(u.x) + wr[t + 1] * bf_hi(u.x);
                dot += wr[t + 2] * bf_lo(u.y) + wr[t + 3] * bf_hi(u.y);
                dot += wr[t + 4] * bf_lo(u.z) + wr[t + 5] * bf_hi(u.z);
                dot += wr[t + 6] * bf_lo(u.w) + wr[t + 7] * bf_hi(u.w);
            }
            unsigned d = ((const unsigned*)q)[24];
            dot += wr[48] * bf_lo(d) + wr[49] * bf_hi(d);
            lsum += logf(dot + 1e-5f);
        }
    }
    float s = waveReduceSum(lsum);
    const int wave = tid >> 6, lane = tid & 63;
    if (lane == 0) swred[wave] = s;
    __syncthreads();
    if (tid == 0) {
        float tot = swred[0] + swred[1] + swred[2] + swred[3];
        atomicAdd(loss, -tot * (1.0f / (float)Bn));
    }
}

extern "C" void kernel_launch(void* const* d_in, const int* in_sizes, int n_in,
                              void* d_out, int out_size, void* d_ws, size_t ws_size,
                              hipStream_t stream) {
    const int*   ids   = (const int*)d_in[0];
    const float* rho   = (const float*)d_in[1];
    const float* alpha = (const float*)d_in[2];
    const float* W1    = (const float*)d_in[3];
    const float* b1    = (const float*)d_in[4];
    const float* Wmu   = (const float*)d_in[5];
    const float* bmu   = (const float*)d_in[6];
    const float* Wlv   = (const float*)d_in[7];
    const float* blv   = (const float*)d_in[8];

    float* theta = (float*)d_out;            // [B, T]
    float* loss  = theta + Bn * Tn;          // scalar at d_out[51200]

    float* ws       = (float*)d_ws;
    float* topicsum = ws;                                    // 64 f
    float* aT       = ws + 64;                               // 300*64 f
    int*   cnt2     = (int*)(aT + En * 64);                  // 2048 i
    int*   toks     = cnt2 + 2 * Bn;                         // B*S i
    float* xbar     = (float*)(toks + Bn * Sn);              // B*E f
    float* hbuf     = xbar + Bn * En;                        // B*H f
    unsigned short* rhoh   = (unsigned short*)(hbuf + Bn * Hn);      // V*E us (30 MB)
    unsigned short* betaUh = rhoh + (size_t)Vn * En;                 // V*64 us (6.4 MB), 16B-aligned

    k0_init<<<(Bn * En + 255) / 256, 256, 0, stream>>>(alpha, aT, topicsum, loss, xbar);
    k4_beta<<<dim3((Vn + VT - 1) / VT, TSPLIT), 256, 0, stream>>>(rho, aT, betaUh, rhoh, topicsum);
    k1_tokens_x<<<dim3(Bn, 2), 256, 0, stream>>>(ids, (const unsigned int*)rhoh, toks, cnt2, xbar);
    k2_h<<<Bn / 8, 256, 0, stream>>>(xbar, cnt2, W1, b1, hbuf);
    k3_theta<<<Bn / 16, 256, 0, stream>>>(hbuf, Wmu, bmu, Wlv, blv, theta, loss);
    k6_recon<<<Bn, 256, 0, stream>>>(toks, cnt2, theta, topicsum, (const unsigned short*)betaUh, loss);
}

// Round 5
// 346.306 us; speedup vs baseline: 1.3183x; 1.3183x over previous
//
#include <hip/hip_runtime.h>
#include <math.h>

// ETM forward. B=1024 S=512 V=50000 E=300 H=800 T=50.
// k0: zero xbar/topicsum/loss + transpose alpha->aT
// k5: rhoh = bf16(rho) streaming cast
// k4: betaU[v,:] = exp(rho[v,:]@alpha^T) -> bf16 128B rows + topicsum
//     (1 v/thread, 50 topics in regs, alpha broadcast from LDS, no TSPLIT)
// k1: token compaction (y=2 halves) + x partial sums from bf16 rho gather
// k2: h=relu(x/n @ W1 + b1)   k3: mu/lv/theta/kl   k6: recon + loss

#define Bn 1024
#define Sn 512
#define Vn 50000
#define En 300
#define Hn 800
#define Tn 50
#define VT4 256            // v per k4 block
#define BSTR 64            // betaU bf16 row stride (ushorts) = 128 B

__device__ __forceinline__ float waveReduceSum(float v) {
    #pragma unroll
    for (int off = 32; off > 0; off >>= 1) v += __shfl_xor(v, off, 64);
    return v;
}
__device__ __forceinline__ float waveReduceMax(float v) {
    #pragma unroll
    for (int off = 32; off > 0; off >>= 1) v = fmaxf(v, __shfl_xor(v, off, 64));
    return v;
}
__device__ __forceinline__ unsigned short f2bf(float x) {
    unsigned u = __float_as_uint(x);
    return (unsigned short)((u + 0x7FFFu + ((u >> 16) & 1u)) >> 16);
}
__device__ __forceinline__ float bf_lo(unsigned u) { return __uint_as_float(u << 16); }
__device__ __forceinline__ float bf_hi(unsigned u) { return __uint_as_float(u & 0xFFFF0000u); }

// Zero xbar/topicsum/loss; transpose alpha[t][e] -> aT[e*64 + t].
__global__ __launch_bounds__(256) void k0_init(
        const float* __restrict__ alpha, float* __restrict__ aT,
        float* __restrict__ topicsum, float* __restrict__ loss,
        float* __restrict__ xbar) {
    const int gid = blockIdx.x * 256 + threadIdx.x;
    if (blockIdx.x == 0) {
        if (threadIdx.x < Tn) topicsum[threadIdx.x] = 0.f;
        if (threadIdx.x == 63) *loss = 0.f;
    }
    if (gid < Bn * En) xbar[gid] = 0.f;
    if (gid < Tn * En) {
        int t = gid / En, e = gid - t * En;
        aT[e * 64 + t] = alpha[t * En + e];
    }
}

// Streaming cast rho -> bf16 (coalesced float4 in, ushort4 out).
__global__ __launch_bounds__(256) void k5_cast(
        const float4* __restrict__ rho4, ushort4* __restrict__ rhoh4, int n4) {
    const int i = blockIdx.x * 256 + threadIdx.x;
    if (i < n4) {
        float4 r = rho4[i];
        ushort4 p;
        p.x = f2bf(r.x); p.y = f2bf(r.y); p.z = f2bf(r.z); p.w = f2bf(r.w);
        rhoh4[i] = p;
    }
}

// betaU[v,t] = exp(sum_e rho[v,e]*alpha[t,e]); topicsum[t] += sum_v.
// One v per thread, all 50 topics in registers. Alpha staged once in LDS
// ([e][52] 16B-aligned rows, broadcast reads = conflict-free). rho row read
// directly to registers (sequential -> L1). No barriers in main loop.
// Epilogue: pack bf16 -> LDS transpose (stride 33) -> coalesced row stores.
__global__ __launch_bounds__(256) void k4_beta(
        const float* __restrict__ rho, const float* __restrict__ aT,
        unsigned int* __restrict__ betaU32, float* __restrict__ topicsum) {
    __shared__ float asl[En * 52];             // 62400 B
    __shared__ unsigned int trans[VT4 * 33];   // 33792 B
    __shared__ float wsum[4][Tn];
    const int tid = threadIdx.x;
    const int v0 = blockIdx.x * VT4;
    const int v = v0 + tid;
    const bool valid = v < Vn;
    const int vload = valid ? v : (Vn - 1);

    // stage alpha once: asl[e*52 + t] = alpha[t][e]
    for (int i = tid; i < En * 52; i += 256) {
        int e = i / 52, t = i - e * 52;
        asl[i] = (t < Tn) ? aT[e * 64 + t] : 0.f;
    }
    __syncthreads();

    const float4* rrow = (const float4*)(rho + (size_t)vload * En);  // 75 float4
    float acc[Tn];
    #pragma unroll
    for (int t = 0; t < Tn; ++t) acc[t] = 0.f;

    for (int c = 0; c < En / 12; ++c) {        // 25 chunks of 12 e
        float4 q0 = rrow[3 * c], q1 = rrow[3 * c + 1], q2 = rrow[3 * c + 2];
        float r[12] = {q0.x, q0.y, q0.z, q0.w, q1.x, q1.y, q1.z, q1.w,
                       q2.x, q2.y, q2.z, q2.w};
        #pragma unroll
        for (int e = 0; e < 12; ++e) {
            const float* a = &asl[(12 * c + e) * 52];
            float re = r[e];
            #pragma unroll
            for (int qq = 0; qq < 12; ++qq) {
                float4 av = *(const float4*)(a + 4 * qq);
                acc[4 * qq]     = fmaf(re, av.x, acc[4 * qq]);
                acc[4 * qq + 1] = fmaf(re, av.y, acc[4 * qq + 1]);
                acc[4 * qq + 2] = fmaf(re, av.z, acc[4 * qq + 2]);
                acc[4 * qq + 3] = fmaf(re, av.w, acc[4 * qq + 3]);
            }
            float2 a2 = *(const float2*)(a + 48);
            acc[48] = fmaf(re, a2.x, acc[48]);
            acc[49] = fmaf(re, a2.y, acc[49]);
        }
    }

    #pragma unroll
    for (int t = 0; t < Tn; ++t) acc[t] = valid ? expf(acc[t]) : 0.f;

    // topicsum: wave reduce per topic, then cross-wave + atomic
    const int wave = tid >> 6, lane = tid & 63;
    #pragma unroll
    for (int t = 0; t < Tn; ++t) {
        float s = waveReduceSum(acc[t]);
        if (lane == 0) wsum[wave][t] = s;
    }

    // pack bf16 pairs into trans (stride 33 dwords -> conflict-free writes)
    #pragma unroll
    for (int i = 0; i < 25; ++i) {
        unsigned pk = (unsigned)f2bf(acc[2 * i]) |
                      ((unsigned)f2bf(acc[2 * i + 1]) << 16);
        trans[tid * 33 + i] = pk;
    }
    #pragma unroll
    for (int i = 25; i < 32; ++i) trans[tid * 33 + i] = 0u;
    __syncthreads();

    if (tid < Tn) {
        atomicAdd(&topicsum[tid],
                  wsum[0][tid] + wsum[1][tid] + wsum[2][tid] + wsum[3][tid]);
    }
    // stream out: 256 rows x 32 dwords, coalesced dword stores (full lines).
    // betaU buffer padded to gridDim*VT4 rows so full-tile store is safe.
    unsigned int* dst = betaU32 + (size_t)v0 * 32;
    for (int j = tid; j < VT4 * 32; j += 256) {
        dst[j] = trans[(j >> 5) * 33 + (j & 31)];
    }
}

// Half-doc token compaction + unscaled x partial sums from bf16 rho gather.
// grid (Bn, 2). Lane p<150 owns e-pair (2p, 2p+1): one dword per token.
__global__ __launch_bounds__(256) void k1_tokens_x(
        const int* __restrict__ ids, const unsigned int* __restrict__ rhoh32,
        int* __restrict__ toks, int* __restrict__ cnt2,
        float* __restrict__ xbar) {
    __shared__ int sid[256];
    __shared__ int scount;
    const int b = blockIdx.x, half = blockIdx.y, tid = threadIdx.x;
    if (tid == 0) scount = 0;
    __syncthreads();
    int id = ids[b * Sn + half * 256 + tid];
    if (id != 1 && id != 2) {
        int p = atomicAdd(&scount, 1);
        sid[p] = id;
    }
    __syncthreads();
    const int n = scount;
    if (tid < n) toks[b * Sn + half * 256 + tid] = sid[tid];
    if (tid == 0) cnt2[b * 2 + half] = n;
    if (tid < En / 2) {
        float ax = 0.f, ay = 0.f;
        for (int s = 0; s < n; ++s) {
            unsigned u = rhoh32[sid[s] * (En / 2) + tid];
            ax += bf_lo(u);
            ay += bf_hi(u);
        }
        atomicAdd(&xbar[b * En + 2 * tid], ax);
        atomicAdd(&xbar[b * En + 2 * tid + 1], ay);
    }
}

// h = relu((xsum/n) @ W1 + b1): 8 rows/block; scale folded into staging.
__global__ __launch_bounds__(256) void k2_h(
        const float* __restrict__ xbar, const int* __restrict__ cnt2,
        const float* __restrict__ W1, const float* __restrict__ b1,
        float* __restrict__ h) {
    const int BR = 8;
    __shared__ float xs[BR * En];
    __shared__ float invn[BR];
    const int b0 = blockIdx.x * BR, tid = threadIdx.x;
    if (tid < BR) {
        int bb = b0 + tid;
        invn[tid] = 1.0f / (float)(cnt2[2 * bb] + cnt2[2 * bb + 1]);
    }
    __syncthreads();
    for (int i = tid; i < BR * En; i += 256) xs[i] = xbar[b0 * En + i] * invn[i / En];
    __syncthreads();
    const int j0 = tid, j1 = tid + 256, j2 = tid + 512, j3 = tid + 768;
    const bool has3 = (j3 < Hn);
    float acc[BR][4];
    #pragma unroll
    for (int r = 0; r < BR; ++r) {
        acc[r][0] = b1[j0]; acc[r][1] = b1[j1]; acc[r][2] = b1[j2];
        acc[r][3] = has3 ? b1[j3] : 0.f;
    }
    for (int e = 0; e < En; ++e) {
        float w0 = W1[e * Hn + j0];
        float w1 = W1[e * Hn + j1];
        float w2 = W1[e * Hn + j2];
        float w3 = has3 ? W1[e * Hn + j3] : 0.f;
        #pragma unroll
        for (int r = 0; r < BR; ++r) {
            float xv = xs[r * En + e];
            acc[r][0] += xv * w0; acc[r][1] += xv * w1;
            acc[r][2] += xv * w2; acc[r][3] += xv * w3;
        }
    }
    #pragma unroll
    for (int r = 0; r < BR; ++r) {
        h[(b0 + r) * Hn + j0] = fmaxf(acc[r][0], 0.f);
        h[(b0 + r) * Hn + j1] = fmaxf(acc[r][1], 0.f);
        h[(b0 + r) * Hn + j2] = fmaxf(acc[r][2], 0.f);
        if (has3) h[(b0 + r) * Hn + j3] = fmaxf(acc[r][3], 0.f);
    }
}

// mu/lv = h@Wmu/Wlv + bias; theta = softmax(mu); kl accumulated into loss.
__global__ __launch_bounds__(256) void k3_theta(
        const float* __restrict__ h, const float* __restrict__ Wmu,
        const float* __restrict__ bmu, const float* __restrict__ Wlv,
        const float* __restrict__ blv, float* __restrict__ theta,
        float* __restrict__ loss) {
    const int BR = 16;
    __shared__ float hs[BR * Hn];    // 51.2 KB
    const int b0 = blockIdx.x * BR, tid = threadIdx.x;
    for (int i = tid; i < BR * Hn; i += 256) hs[i] = h[b0 * Hn + i];
    __syncthreads();
    const int wave = tid >> 6, lane = tid & 63;
    const int t = (lane < Tn) ? lane : (Tn - 1);
    const bool act = (lane < Tn);
    float amu[4], alv[4];
    #pragma unroll
    for (int k = 0; k < 4; ++k) { amu[k] = bmu[t]; alv[k] = blv[t]; }
    const int rbase = wave * 4;
    for (int j = 0; j < Hn; ++j) {
        float wm = Wmu[j * Tn + t];
        float wl = Wlv[j * Tn + t];
        #pragma unroll
        for (int k = 0; k < 4; ++k) {
            float hv = hs[(rbase + k) * Hn + j];
            amu[k] += hv * wm;
            alv[k] += hv * wl;
        }
    }
    float klacc = 0.f;
    #pragma unroll
    for (int k = 0; k < 4; ++k) {
        float mu = amu[k], lv = alv[k];
        float m = waveReduceMax(act ? mu : -1e30f);
        float ex = act ? expf(mu - m) : 0.f;
        float ssum = waveReduceSum(ex);
        if (act) theta[(b0 + rbase + k) * Tn + lane] = ex / ssum;
        klacc += waveReduceSum(act ? (1.f + lv - mu * mu - expf(lv)) : 0.f);
    }
    if (lane == 0) atomicAdd(loss, -0.5f * klacc * (1.0f / (float)Bn));
}

// recon[b] = -sum_tok log( sum_t (theta/Z)[t] * betaU[tok,t] + 1e-5 ).
// betaU bf16, 128B rows: one cache line per token; uint4 loads.
__global__ __launch_bounds__(256) void k6_recon(
        const int* __restrict__ toks, const int* __restrict__ cnt2,
        const float* __restrict__ theta, const float* __restrict__ topicsum,
        const unsigned short* __restrict__ betaUh, float* __restrict__ loss) {
    __shared__ float sw[Tn];
    __shared__ float swred[4];
    const int b = blockIdx.x, tid = threadIdx.x;
    if (tid < Tn) sw[tid] = theta[b * Tn + tid] / topicsum[tid];
    __syncthreads();
    float wr[Tn];
    #pragma unroll
    for (int t = 0; t < Tn; ++t) wr[t] = sw[t];
    float lsum = 0.f;
    for (int half = 0; half < 2; ++half) {
        const int n = cnt2[b * 2 + half];
        for (int i = tid; i < n; i += 256) {
            int v = toks[b * Sn + half * 256 + i];
            const uint4* q = (const uint4*)(betaUh + (size_t)v * BSTR);
            float dot = 0.f;
            #pragma unroll
            for (int k = 0; k < 6; ++k) {
                uint4 u = q[k];
                int t = 8 * k;
                dot += wr[t]     * bf_lo(u.x) + wr[t + 1] * bf_hi(u.x);
                dot += wr[t + 2] * bf_lo(u.y) + wr[t + 3] * bf_hi(u.y);
                dot += wr[t + 4] * bf_lo(u.z) + wr[t + 5] * bf_hi(u.z);
                dot += wr[t + 6] * bf_lo(u.w) + wr[t + 7] * bf_hi(u.w);
            }
            unsigned d = ((const unsigned*)q)[24];
            dot += wr[48] * bf_lo(d) + wr[49] * bf_hi(d);
            lsum += logf(dot + 1e-5f);
        }
    }
    float s = waveReduceSum(lsum);
    const int wave = tid >> 6, lane = tid & 63;
    if (lane == 0) swred[wave] = s;
    __syncthreads();
    if (tid == 0) {
        float tot = swred[0] + swred[1] + swred[2] + swred[3];
        atomicAdd(loss, -tot * (1.0f / (float)Bn));
    }
}

extern "C" void kernel_launch(void* const* d_in, const int* in_sizes, int n_in,
                              void* d_out, int out_size, void* d_ws, size_t ws_size,
                              hipStream_t stream) {
    const int*   ids   = (const int*)d_in[0];
    const float* rho   = (const float*)d_in[1];
    const float* alpha = (const float*)d_in[2];
    const float* W1    = (const float*)d_in[3];
    const float* b1    = (const float*)d_in[4];
    const float* Wmu   = (const float*)d_in[5];
    const float* bmu   = (const float*)d_in[6];
    const float* Wlv   = (const float*)d_in[7];
    const float* blv   = (const float*)d_in[8];

    float* theta = (float*)d_out;            // [B, T]
    float* loss  = theta + Bn * Tn;          // scalar at d_out[51200]

    const int k4grid = (Vn + VT4 - 1) / VT4;           // 196
    char* w = (char*)d_ws;
    float* topicsum = (float*)w;               w += 256;                     // 64 f
    float* aT       = (float*)w;               w += En * 64 * 4;             // 76.8 KB
    int*   cnt2     = (int*)w;                 w += 2 * Bn * 4;
    int*   toks     = (int*)w;                 w += Bn * Sn * 4;
    float* xbar     = (float*)w;               w += Bn * En * 4;
    float* hbuf     = (float*)w;               w += Bn * Hn * 4;
    unsigned int* rhoh32 = (unsigned int*)w;   w += (size_t)Vn * En * 2;     // 30 MB bf16
    unsigned int* betaU32 = (unsigned int*)w;  w += (size_t)k4grid * VT4 * 128;  // padded rows

    k0_init<<<(Bn * En + 255) / 256, 256, 0, stream>>>(alpha, aT, topicsum, loss, xbar);
    k5_cast<<<(Vn * En / 4 + 255) / 256, 256, 0, stream>>>(
        (const float4*)rho, (ushort4*)rhoh32, Vn * En / 4);
    k4_beta<<<k4grid, 256, 0, stream>>>(rho, aT, betaU32, topicsum);
    k1_tokens_x<<<dim3(Bn, 2), 256, 0, stream>>>(ids, rhoh32, toks, cnt2, xbar);
    k2_h<<<Bn / 8, 256, 0, stream>>>(xbar, cnt2, W1, b1, hbuf);
    k3_theta<<<Bn / 16, 256, 0, stream>>>(hbuf, Wmu, bmu, Wlv, blv, theta, loss);
    k6_recon<<<Bn, 256, 0, stream>>>(toks, cnt2, theta, topicsum,
                                     (const unsigned short*)betaU32, loss);
}